// Round 8
// baseline (240.951 us; speedup 1.0000x reference)
//
#include <hip/hip_runtime.h>
#include <math.h>

#define NTOK 2304      // 48*48 tokens
#define BATCH 2
#define CIN 256
#define HID 512        // 8 heads * 64
#define NH 8
#define LOG2E 1.44269504088896340736f

typedef __attribute__((ext_vector_type(8))) short bfrag;    // 8 bf16 (4 VGPRs)
typedef __attribute__((ext_vector_type(16))) float f32x16;  // MFMA 32x32 accumulator

#if __has_builtin(__builtin_amdgcn_exp2f)
#define EXP2(x) __builtin_amdgcn_exp2f(x)
#else
#define EXP2(x) exp2f(x)
#endif

// fp32 -> bf16 (RNE)
__device__ __forceinline__ unsigned f2bf(float f) {
    unsigned u = __float_as_uint(f);
    u += 0x7FFF + ((u >> 16) & 1);
    return u >> 16;
}

// pack trunc(hi(b)) , trunc(hi(a)) -> one dword {bf16(b):bf16(a)} in 1 v_perm
__device__ __forceinline__ unsigned pk_trunc(float a, float b) {
    return __builtin_amdgcn_perm(__float_as_uint(b), __float_as_uint(a), 0x07060302u);
}

// exp2 + bf16-pack + lane^32 half-swap: accS (S^T quadrant, C-layout) ->
// two A-operand P frags; accumulates this lane's partial row sums.
__device__ __forceinline__ void softmax_frag(
    const f32x16& accS, int h, float& ps0, float& ps1, bfrag& P0, bfrag& P1)
{
    unsigned dw[8];
#pragma unroll
    for (int i = 0; i < 8; i++) {
        float plo = EXP2(accS[2 * i]);
        float phi = EXP2(accS[2 * i + 1]);
        dw[i] = pk_trunc(plo, phi);
        ps0 += __uint_as_float(dw[i] << 16);
        ps1 += __uint_as_float(dw[i] & 0xffff0000u);
    }
    unsigned sa0 = h ? dw[0] : dw[2], sb0 = h ? dw[1] : dw[3];
    unsigned sa1 = h ? dw[4] : dw[6], sb1 = h ? dw[5] : dw[7];
    unsigned ra0 = (unsigned)__shfl_xor((int)sa0, 32, 64);
    unsigned rb0 = (unsigned)__shfl_xor((int)sb0, 32, 64);
    unsigned ra1 = (unsigned)__shfl_xor((int)sa1, 32, 64);
    unsigned rb1 = (unsigned)__shfl_xor((int)sb1, 32, 64);
    union { bfrag f; unsigned u[4]; } U0, U1;
    U0.u[0] = h ? ra0 : dw[0];  U0.u[1] = h ? rb0 : dw[1];
    U0.u[2] = h ? dw[2] : ra0;  U0.u[3] = h ? dw[3] : rb0;
    U1.u[0] = h ? ra1 : dw[4];  U1.u[1] = h ? rb1 : dw[5];
    U1.u[2] = h ? dw[6] : ra1;  U1.u[3] = h ? dw[7] : rb1;
    P0 = U0.f; P1 = U1.f;
}

// ---------------------------------------------------------------------------
// Fused input pack: blocks [0,256) pack both weight matrices elementwise;
// blocks [256,544) transpose-pack x fp32 [b][256][2304] -> bf16 xT [b][n][256].
// ---------------------------------------------------------------------------
__global__ __launch_bounds__(256) void pack_inputs(
    const float* __restrict__ wq, short* __restrict__ wqb,
    const float* __restrict__ wp, short* __restrict__ wpb,
    const float* __restrict__ x, short* __restrict__ xT)
{
    int bid = blockIdx.x;
    int tid = threadIdx.x;
    if (bid < 256) {
        int e = (bid * 256 + tid) * 8;
        const int NQ = 1536 * 256;
        const float* src; short* dst;
        if (e < NQ) { src = wq + e; dst = wqb + e; }
        else        { src = wp + (e - NQ); dst = wpb + (e - NQ); }
        float4 v0 = ((const float4*)src)[0];
        float4 v1 = ((const float4*)src)[1];
        unsigned b0 = f2bf(v0.x) | (f2bf(v0.y) << 16);
        unsigned b1 = f2bf(v0.z) | (f2bf(v0.w) << 16);
        unsigned b2 = f2bf(v1.x) | (f2bf(v1.y) << 16);
        unsigned b3 = f2bf(v1.z) | (f2bf(v1.w) << 16);
        *((uint4*)dst) = make_uint4(b0, b1, b2, b3);
        return;
    }
    int idx = bid - 256;                 // 288 transpose tiles
    int n0 = (idx % 36) * 64;
    int c0 = ((idx / 36) & 3) * 64;
    int b = idx / 144;
    __shared__ float sT[64][65];
    int lane = tid & 63, wv = tid >> 6;
    for (int c = wv; c < 64; c += 4)
        sT[c][lane] = x[((size_t)b * CIN + c0 + c) * NTOK + n0 + lane];
    __syncthreads();
    int n = tid >> 2, c4 = (tid & 3) * 16;
    unsigned buf[8];
#pragma unroll
    for (int i = 0; i < 8; i++)
        buf[i] = f2bf(sT[c4 + 2 * i][n]) | (f2bf(sT[c4 + 2 * i + 1][n]) << 16);
    short* dst = xT + ((size_t)b * NTOK + n0 + n) * CIN + c0 + c4;
    ((uint4*)dst)[0] = make_uint4(buf[0], buf[1], buf[2], buf[3]);
    ((uint4*)dst)[1] = make_uint4(buf[4], buf[5], buf[6], buf[7]);
}

// ---------------------------------------------------------------------------
// QKV GEMM (MFMA): BM=128, BN=128, K=256. rows o<1024 (q,k) -> fp32 qkf;
// rows >=1024 (v) -> bf16 vb [b][512][NTOK]. grid (18, 12, 2).
// ---------------------------------------------------------------------------
__global__ __launch_bounds__(256, 2) void gemm_qkv(
    const short* __restrict__ A, const short* __restrict__ B,
    float* __restrict__ qkf, short* __restrict__ vb)
{
    const int K = CIN;
    int b = blockIdx.z;
    int o0 = blockIdx.y * 128;
    int n0 = blockIdx.x * 128;
    int tid = threadIdx.x, wv = tid >> 6, lane = tid & 63;
    int h = lane >> 5, l31 = lane & 31;

    const short* pa = A + (size_t)(o0 + l31) * K + h * 8;
    const short* pb = B + ((size_t)b * NTOK + n0 + wv * 32 + l31) * K + h * 8;

    f32x16 acc[4];
#pragma unroll
    for (int rb = 0; rb < 4; rb++)
#pragma unroll
        for (int r = 0; r < 16; r++) acc[rb][r] = 0.f;

#pragma unroll 2
    for (int kt = 0; kt < K; kt += 16) {
        bfrag a0 = *(const bfrag*)(pa + kt);
        bfrag a1 = *(const bfrag*)(pa + (size_t)32 * K + kt);
        bfrag a2 = *(const bfrag*)(pa + (size_t)64 * K + kt);
        bfrag a3 = *(const bfrag*)(pa + (size_t)96 * K + kt);
        bfrag bb = *(const bfrag*)(pb + kt);
        acc[0] = __builtin_amdgcn_mfma_f32_32x32x16_bf16(a0, bb, acc[0], 0, 0, 0);
        acc[1] = __builtin_amdgcn_mfma_f32_32x32x16_bf16(a1, bb, acc[1], 0, 0, 0);
        acc[2] = __builtin_amdgcn_mfma_f32_32x32x16_bf16(a2, bb, acc[2], 0, 0, 0);
        acc[3] = __builtin_amdgcn_mfma_f32_32x32x16_bf16(a3, bb, acc[3], 0, 0, 0);
    }

    int nn = n0 + wv * 32 + l31;
    if (o0 < 1024) {
        float* Q = qkf + (size_t)b * 1024 * NTOK;
#pragma unroll
        for (int rb = 0; rb < 4; rb++)
#pragma unroll
            for (int r = 0; r < 16; r++) {
                int ml = (r & 3) + 8 * (r >> 2) + 4 * h;
                Q[(size_t)(o0 + rb * 32 + ml) * NTOK + nn] = acc[rb][r];
            }
    } else {
        short* V = vb + (size_t)b * 512 * NTOK;
        int ov = o0 - 1024;
#pragma unroll
        for (int rb = 0; rb < 4; rb++)
#pragma unroll
            for (int r = 0; r < 16; r++) {
                int ml = (r & 3) + 8 * (r >> 2) + 4 * h;
                V[(size_t)(ov + rb * 32 + ml) * NTOK + nn] = (short)f2bf(acc[rb][r]);
            }
    }
}

// ---------------------------------------------------------------------------
// Row inverse L2-norm over tokens (float4 reads). rows 0..2047.
// ---------------------------------------------------------------------------
__global__ __launch_bounds__(256) void rownorm(
    const float* __restrict__ qkf, float* __restrict__ invn)
{
    int row = blockIdx.x;
    int b = row >> 10, o = row & 1023;
    const float* p = qkf + ((size_t)b * 1024 + o) * NTOK;
    int tid = threadIdx.x;
    float s = 0.f;
    for (int i = tid; i < NTOK / 4; i += 256) {
        float4 v = ((const float4*)p)[i];
        s += v.x * v.x + v.y * v.y + v.z * v.z + v.w * v.w;
    }
#pragma unroll
    for (int off = 32; off > 0; off >>= 1) s += __shfl_down(s, off, 64);
    __shared__ float ws[4];
    if ((tid & 63) == 0) ws[tid >> 6] = s;
    __syncthreads();
    if (tid == 0) {
        float tot = ws[0] + ws[1] + ws[2] + ws[3];
        invn[row] = 1.f / fmaxf(sqrtf(tot), 1e-12f);
    }
}

// ---------------------------------------------------------------------------
// Pack normalized q,k -> bf16 token-major qkt [sel][bh][n][64].
// q additionally scaled by log2(e) so attention uses exp2 directly.
// ---------------------------------------------------------------------------
__global__ __launch_bounds__(256) void pack_qk(
    const float* __restrict__ qkf, const float* __restrict__ invn,
    short* __restrict__ qkt)
{
    int n0 = blockIdx.x * 64;
    int bh = blockIdx.y;
    int sel = blockIdx.z;
    int b = bh >> 3, h = bh & 7;
    const float* src = qkf + ((size_t)b * 1024 + sel * 512 + h * 64) * NTOK;
    int base = b * 1024 + sel * 512 + h * 64;
    float extra = sel == 0 ? LOG2E : 1.f;

    __shared__ float sT[64][65];
    int tid = threadIdx.x, lane = tid & 63, wv = tid >> 6;
    for (int d = wv; d < 64; d += 4)
        sT[d][lane] = src[(size_t)d * NTOK + n0 + lane] * (invn[base + d] * extra);
    __syncthreads();

    int n = tid >> 2, c4 = (tid & 3) * 16;
    unsigned buf[8];
#pragma unroll
    for (int i = 0; i < 8; i++)
        buf[i] = f2bf(sT[c4 + 2 * i][n]) | (f2bf(sT[c4 + 2 * i + 1][n]) << 16);
    short* dst = qkt + (size_t)sel * ((size_t)16 * NTOK * 64)
                     + ((size_t)bh * NTOK + n0 + n) * 64 + c4;
    ((uint4*)dst)[0] = make_uint4(buf[0], buf[1], buf[2], buf[3]);
    ((uint4*)dst)[1] = make_uint4(buf[4], buf[5], buf[6], buf[7]);
}

// ---------------------------------------------------------------------------
// Barrier-free attention, high-TLP + XCD locality.
// 1-D grid 576: g = bid & 31 -> (bh, ms); ntile = bid >> 5 in [0,18).
// Sharers of one (bh,ms) K/V-set differ by 32 (= 0 mod 8) -> same XCD ->
// K/V L2-resident (R7: FETCH 40->9 MB). Wave owns 32 n; block covers 128 n.
// launch_bounds(256,3): all 576 blocks co-resident (<=96/XCD), 2.25 w/SIMD.
// ---------------------------------------------------------------------------
__global__ __launch_bounds__(256, 3) void attn_nb(
    const short* __restrict__ qkt,   // [2][16][2304][64] bf16 (q pre-scaled log2e)
    const short* __restrict__ vb,    // [2][512][2304] bf16
    float* __restrict__ Opart,       // [2 split][2][2304][512] fp32
    float* __restrict__ lsum)        // [2 split][16][2304] fp32
{
    int bid = blockIdx.x;
    int g = bid & 31;
    int bh = g >> 1, ms = g & 1;
    int ntile = bid >> 5;
    int b = bh >> 3, hh = bh & 7;
    int tid = threadIdx.x, wv = tid >> 6, lane = tid & 63;
    int h = lane >> 5, l31 = lane & 31;
    int nb = ntile * 128 + wv * 32;
    int mbase = ms * (NTOK / 2);

    const short* Qrow = qkt + ((size_t)bh * NTOK + nb + l31) * 64 + h * 8;
    const short* kp = qkt + (size_t)16 * NTOK * 64
                    + ((size_t)bh * NTOK + mbase + l31) * 64 + h * 8;
    const short* vl = vb + ((size_t)b * 512 + hh * 64 + l31) * NTOK + mbase + h * 8;
    const short* vh2 = vl + (size_t)32 * NTOK;

    bfrag bQ[4];
#pragma unroll
    for (int i = 0; i < 4; i++) bQ[i] = *(const bfrag*)(Qrow + i * 16);

    f32x16 aL, aH;
#pragma unroll
    for (int r = 0; r < 16; r++) { aL[r] = 0.f; aH[r] = 0.f; }
    float ps0 = 0.f, ps1 = 0.f;

#pragma unroll 2
    for (int it = 0; it < 36; it++) {
        bfrag k0 = *(const bfrag*)(kp);
        bfrag k1 = *(const bfrag*)(kp + 16);
        bfrag k2 = *(const bfrag*)(kp + 32);
        bfrag k3 = *(const bfrag*)(kp + 48);
        bfrag v00 = *(const bfrag*)(vl);
        bfrag v01 = *(const bfrag*)(vl + 16);
        bfrag v10 = *(const bfrag*)(vh2);
        bfrag v11 = *(const bfrag*)(vh2 + 16);
        kp += 2048; vl += 32; vh2 += 32;

        f32x16 accS;
#pragma unroll
        for (int r = 0; r < 16; r++) accS[r] = 0.f;
        accS = __builtin_amdgcn_mfma_f32_32x32x16_bf16(k0, bQ[0], accS, 0, 0, 0);
        accS = __builtin_amdgcn_mfma_f32_32x32x16_bf16(k1, bQ[1], accS, 0, 0, 0);
        accS = __builtin_amdgcn_mfma_f32_32x32x16_bf16(k2, bQ[2], accS, 0, 0, 0);
        accS = __builtin_amdgcn_mfma_f32_32x32x16_bf16(k3, bQ[3], accS, 0, 0, 0);

        bfrag P0, P1;
        softmax_frag(accS, h, ps0, ps1, P0, P1);

        aL = __builtin_amdgcn_mfma_f32_32x32x16_bf16(P0, v00, aL, 0, 0, 0);
        aL = __builtin_amdgcn_mfma_f32_32x32x16_bf16(P1, v01, aL, 0, 0, 0);
        aH = __builtin_amdgcn_mfma_f32_32x32x16_bf16(P0, v10, aH, 0, 0, 0);
        aH = __builtin_amdgcn_mfma_f32_32x32x16_bf16(P1, v11, aH, 0, 0, 0);
    }

    float pst = ps0 + ps1;
    pst += __shfl_xor(pst, 32, 64);
    if (h == 0)
        lsum[((size_t)ms * 16 + bh) * NTOK + nb + l31] = pst;

    float* Ob = Opart + (size_t)ms * (2ull * NTOK * HID)
              + (size_t)b * NTOK * HID + hh * 64;
#pragma unroll
    for (int r = 0; r < 16; r++) {
        int ml = (r & 3) + 8 * (r >> 2) + 4 * h;
        Ob[(size_t)(nb + ml) * HID + l31] = aL[r];
        Ob[(size_t)(nb + ml) * HID + 32 + l31] = aH[r];
    }
}

// ---------------------------------------------------------------------------
// Proj GEMM fused with split-combine + normalize: reads Opart (2 fp32 splits)
// + lsum, builds normalized bf16 B-frags in-register, y = wp @ ao + bias.
// BM=64, BN=64; grid (36, 4, 2); wave = (o-half, n-half).
// ---------------------------------------------------------------------------
__global__ __launch_bounds__(256, 2) void gemm_proj(
    const short* __restrict__ wpb, const float* __restrict__ Opart,
    const float* __restrict__ lsum, const float* __restrict__ bias,
    float* __restrict__ y)
{
    const int K = HID;
    int b = blockIdx.z;
    int o0 = blockIdx.y * 64;
    int n0 = blockIdx.x * 64;
    int tid = threadIdx.x, wv = tid >> 6, lane = tid & 63;
    int h = lane >> 5, l31 = lane & 31;
    int ow = o0 + (wv & 1) * 32;
    int nn = n0 + (wv >> 1) * 32 + l31;

    // per-lane inverse row sums for all 8 heads at token nn
    float inv[8];
#pragma unroll
    for (int hd = 0; hd < 8; hd++) {
        float l0 = lsum[(size_t)(b * 8 + hd) * NTOK + nn];
        float l1 = lsum[(size_t)(16 + b * 8 + hd) * NTOK + nn];
        inv[hd] = 1.f / (l0 + l1);
    }

    const short* pa = wpb + (size_t)(ow + l31) * K + h * 8;
    const float* pb0 = Opart + ((size_t)b * NTOK + nn) * HID + h * 8;
    const float* pb1 = pb0 + (size_t)2 * NTOK * HID;

    f32x16 acc;
#pragma unroll
    for (int r = 0; r < 16; r++) acc[r] = 0.f;

#pragma unroll 2
    for (int kt = 0; kt < K; kt += 16) {
        bfrag a = *(const bfrag*)(pa + kt);
        float4 q0 = ((const float4*)(pb0 + kt))[0];
        float4 q1 = ((const float4*)(pb0 + kt))[1];
        float4 r0 = ((const float4*)(pb1 + kt))[0];
        float4 r1 = ((const float4*)(pb1 + kt))[1];
        float iv = inv[(kt + h * 8) >> 6];
        float e0 = (q0.x + r0.x) * iv, e1 = (q0.y + r0.y) * iv;
        float e2 = (q0.z + r0.z) * iv, e3 = (q0.w + r0.w) * iv;
        float e4 = (q1.x + r1.x) * iv, e5 = (q1.y + r1.y) * iv;
        float e6 = (q1.z + r1.z) * iv, e7 = (q1.w + r1.w) * iv;
        union { bfrag f; unsigned u[4]; } B;
        B.u[0] = f2bf(e0) | (f2bf(e1) << 16);
        B.u[1] = f2bf(e2) | (f2bf(e3) << 16);
        B.u[2] = f2bf(e4) | (f2bf(e5) << 16);
        B.u[3] = f2bf(e6) | (f2bf(e7) << 16);
        acc = __builtin_amdgcn_mfma_f32_32x32x16_bf16(a, B.f, acc, 0, 0, 0);
    }

#pragma unroll
    for (int r = 0; r < 16; r++) {
        int o = ow + (r & 3) + 8 * (r >> 2) + 4 * h;
        y[((size_t)b * CIN + o) * NTOK + nn] = acc[r] + bias[o];
    }
}

// ---------------------------------------------------------------------------
// Workspace (<= 36,446,208 B of 37,748,736):
//   [0, 18,874,368)           qkf fp32 [2][1024][2304]   (k2 -> k4)
//       then Opart fp32 [2 split][2][2304][512]          (k5 -> k6, exact fit)
//   [18,874,368, 23,592,960)  vb bf16 [2][512][2304]     (k2 -> k5)
//   [23,592,960, 33,030,144)  qkt bf16 [2][16][2304][64] (k4 -> k5)
//   [33,030,144, 33,325,056)  lsum fp32 [2][16][2304]    (k5 -> k6, over dead xT)
//   [33,030,144, 35,389,440)  xT bf16                     (k1 -> k2, dead at k5)
//   [35,389,440, 36,175,872)  wqb bf16
//   [36,175,872, 36,438,016)  wpb bf16
//   [36,438,016, 36,446,208)  invn fp32 [2048]
// ---------------------------------------------------------------------------
extern "C" void kernel_launch(void* const* d_in, const int* in_sizes, int n_in,
                              void* d_out, int out_size, void* d_ws, size_t ws_size,
                              hipStream_t stream)
{
    const float* x      = (const float*)d_in[0];
    const float* w_qkv  = (const float*)d_in[1];
    const float* w_proj = (const float*)d_in[2];
    const float* b_proj = (const float*)d_in[3];
    float* y = (float*)d_out;

    float* qkf   = (float*)d_ws;
    float* Opart = (float*)d_ws;
    short* vb    = (short*)((char*)d_ws + 18874368);
    short* qkt   = (short*)((char*)d_ws + 23592960);
    float* lsum  = (float*)((char*)d_ws + 33030144);
    short* xT    = (short*)((char*)d_ws + 33030144);
    short* wqb   = (short*)((char*)d_ws + 35389440);
    short* wpb   = (short*)((char*)d_ws + 36175872);
    float* invn  = (float*)((char*)d_ws + 36438016);

    // k1: pack weights + transpose-pack x (one dispatch)
    pack_inputs<<<544, 256, 0, stream>>>(w_qkv, wqb, w_proj, wpb, x, xT);
    // k2: QKV GEMM, BM=128 (q,k fp32; v straight to bf16)
    gemm_qkv<<<dim3(NTOK / 128, 1536 / 128, BATCH), 256, 0, stream>>>(
        wqb, xT, qkf, vb);
    // k3: inverse row norms (float4)
    rownorm<<<2048, 256, 0, stream>>>(qkf, invn);
    // k4: pack normalized q (x log2e), k -> token-major bf16
    pack_qk<<<dim3(NTOK / 64, BATCH * NH, 2), 256, 0, stream>>>(qkf, invn, qkt);
    // k5: attention — 576 blocks, XCD-swizzled, 2.25 waves/SIMD
    attn_nb<<<576, 256, 0, stream>>>(qkt, vb, Opart, lsum);
    // k6: proj GEMM fused with combine/normalize + bias
    gemm_proj<<<dim3(NTOK / 64, CIN / 64, BATCH), 256, 0, stream>>>(
        wpb, Opart, lsum, b_proj, y);
}